// Round 8
// baseline (433.230 us; speedup 1.0000x reference)
//
#include <hip/hip_runtime.h>
#include <math.h>

#define V 8192
#define D 128
#define NH 8
#define HD 16
#define SEQ 128
#define HID 341
#define EPS 1e-6f

__device__ __forceinline__ float sigm(float x) { return 1.0f / (1.0f + __expf(-x)); }

// 256-thread block-wide sum. scratch >= 4 floats. 2 barriers.
__device__ __forceinline__ float block_sum256(float v, float* scratch) {
    #pragma unroll
    for (int m = 32; m > 0; m >>= 1) v += __shfl_xor(v, m);
    if ((threadIdx.x & 63) == 0) scratch[threadIdx.x >> 6] = v;
    __syncthreads();
    float s = (scratch[0] + scratch[1]) + (scratch[2] + scratch[3]);
    __syncthreads();
    return s;
}

// Coalesced register-prefetch helpers (NF4 float4s spread over 256 threads).
template <int NF4>
__device__ __forceinline__ void pf_load(float4* v, const float* src, int t) {
    const float4* s4 = (const float4*)src;
    #pragma unroll
    for (int i = 0; i < (NF4 + 255) / 256; ++i) {
        int idx = t + i * 256;
        if (idx < NF4) v[i] = s4[idx];
    }
}
template <int NF4>
__device__ __forceinline__ void pf_store(const float4* v, float* dst, int t) {
    float4* d4 = (float4*)dst;
    #pragma unroll
    for (int i = 0; i < (NF4 + 255) / 256; ++i) {
        int idx = t + i * 256;
        if (idx < NF4) d4[idx] = v[i];
    }
}

// K1: embed + rms + qkv + rope. grid = SEQ + 256 (warm blocks), block=256
__global__ __launch_bounds__(256, 1) void k_embed_qkv(
    const int* __restrict__ idx, const float* __restrict__ w_raw,
    const float* __restrict__ wq, const float* __restrict__ wk,
    const float* __restrict__ wv, const float* __restrict__ n1w,
    const float* __restrict__ w1, const float* __restrict__ w3,
    const float* __restrict__ w2, const float* __restrict__ wo,
    float* __restrict__ x, float* __restrict__ q, float* __restrict__ k,
    float* __restrict__ v, float* __restrict__ sink) {
    int t = threadIdx.x;
    if (blockIdx.x >= SEQ) {
        // L3-warm: stream every weight once
        int g = (blockIdx.x - SEQ) * 256 + t;  // 0..65535
        float acc = 0.f;
        const float4* p = (const float4*)w_raw;
        for (int i = g; i < 262144; i += 65536) {
            float4 u = p[i];
            acc += u.x + u.y + u.z + u.w;
        }
        p = (const float4*)w1;
        if (g < 21824) { float4 u = p[g]; acc += u.x + u.y + u.z + u.w; }
        p = (const float4*)w3;
        if (g < 21824) { float4 u = p[g]; acc += u.x + u.y + u.z + u.w; }
        p = (const float4*)w2;
        if (g < 21824) { float4 u = p[g]; acc += u.x + u.y + u.z + u.w; }
        p = (const float4*)wq;
        if (g < 8192) { float4 u = p[g]; acc += u.x + u.y + u.z + u.w; }
        p = (const float4*)wk;
        if (g < 8192) { float4 u = p[g]; acc += u.x + u.y + u.z + u.w; }
        p = (const float4*)wv;
        if (g < 8192) { float4 u = p[g]; acc += u.x + u.y + u.z + u.w; }
        p = (const float4*)wo;
        if (g < 8192) { float4 u = p[g]; acc += u.x + u.y + u.z + u.w; }
        if (acc == 1234.5678f) sink[0] = acc;
        return;
    }
    __shared__ float hr[D], qrow[D], krow[D], vpart[2][D], scr[4];
    int s = blockIdx.x;
    int col = t & 127, half = t >> 7, dlo = half * 64;
    float xv = 0.f;
    if (t < 128) xv = sigm(w_raw[t * V + idx[s]]);
    if (t < 128) x[s * D + t] = xv;
    float ss = block_sum256(xv * xv, scr);
    float r = 1.0f / sqrtf(ss * (1.0f / D) + EPS);
    if (t < 128) hr[t] = xv * r * n1w[t];
    __syncthreads();
    const float* wsel = (t < 128) ? wq : wk;
    float a0 = 0, a1 = 0, a2 = 0, a3 = 0;
    #pragma unroll 8
    for (int d = 0; d < 128; d += 4) {
        a0 += hr[d] * wsel[d * D + col];
        a1 += hr[d + 1] * wsel[(d + 1) * D + col];
        a2 += hr[d + 2] * wsel[(d + 2) * D + col];
        a3 += hr[d + 3] * wsel[(d + 3) * D + col];
    }
    float qk = (a0 + a1) + (a2 + a3);
    float b0 = 0, b1 = 0, b2 = 0, b3 = 0;
    #pragma unroll 8
    for (int d = dlo; d < dlo + 64; d += 4) {
        b0 += hr[d] * wv[d * D + col];
        b1 += hr[d + 1] * wv[(d + 1) * D + col];
        b2 += hr[d + 2] * wv[(d + 2) * D + col];
        b3 += hr[d + 3] * wv[(d + 3) * D + col];
    }
    vpart[half][col] = (b0 + b1) + (b2 + b3);
    if (t < 128) qrow[col] = qk;
    else krow[col] = qk;
    __syncthreads();
    if (t < 128) {
        v[s * D + t] = vpart[0][t] + vpart[1][t];
        int c = t & (HD - 1);
        int m = c >> 1;
        float fr = (float)s * expf(-(float)m * 1.15129254649702283e+00f);
        float cs = cosf(fr), sn = sinf(fr);
        int base = t & ~1;
        float qe = qrow[base], qod = qrow[base + 1];
        float ke = krow[base], kod = krow[base + 1];
        q[s * D + t] = (c & 1) ? (qe * sn + qod * cs) : (qe * cs - qod * sn);
        k[s * D + t] = (c & 1) ? (ke * sn + kod * cs) : (ke * cs - kod * sn);
    }
}

// K2/K3: fused layer per row; ALL weight/V matrices staged into LDS with
// lane-coalesced float4 loads. grid=SEQ, block=256, 1 block/CU (LDS ~140KB).
template <int MODE>
__global__ __launch_bounds__(256, 1) void k_layer(
    const float* __restrict__ q, const float* __restrict__ kg,
    const float* __restrict__ vg, float* __restrict__ x,
    const float* __restrict__ wo, const float* __restrict__ n2w,
    const float* __restrict__ w1, const float* __restrict__ w3,
    const float* __restrict__ w2, const float* __restrict__ wq,
    const float* __restrict__ wk, const float* __restrict__ wv,
    const float* __restrict__ n1w, float* __restrict__ qo, float* __restrict__ ko,
    float* __restrict__ vo, const float* __restrict__ fw, float* __restrict__ xng) {
    __shared__ float B0[32768];       // 128 KB staging region (reused per phase)
    __shared__ float ps[NH][SEQ + 2];
    __shared__ float qs[D], orow[D], h2[D], qrow[D], krow[D];
    __shared__ float part[2][D];
    __shared__ float af[344];
    __shared__ float rl[NH];
    __shared__ float scr[4];
    int s = blockIdx.x, t = threadIdx.x;
    int col = t & 127, half = t >> 7;

    // Phase A: stage V (16384 floats) + wo (16384) coalesced; overlaps scores.
    {
        const float4* v4 = (const float4*)vg;
        const float4* o4 = (const float4*)wo;
        float4* d0 = (float4*)B0;           // vsh
        float4* d1 = (float4*)(B0 + 16384); // wosh
        #pragma unroll
        for (int i = 0; i < 16; ++i) {
            d0[t + i * 256] = v4[t + i * 256];
            d1[t + i * 256] = o4[t + i * 256];
        }
    }
    float xr = 0.f;
    if (t < 128) {
        qs[t] = q[s * D + t];
        xr = x[s * D + t];
    }
    __syncthreads();

    // scores: thread (j=col, heads half+2u); K direct from global
    {
        int j = col;
        #pragma unroll
        for (int u = 0; u < 4; ++u) {
            int h = half + 2 * u;
            const float4* kp = (const float4*)&kg[j * D + h * HD];
            float4 k0 = kp[0], k1 = kp[1], k2 = kp[2], k3 = kp[3];
            const float* qh = &qs[h * HD];
            float acc = k0.x * qh[0] + k0.y * qh[1] + k0.z * qh[2] + k0.w * qh[3] +
                        k1.x * qh[4] + k1.y * qh[5] + k1.z * qh[6] + k1.w * qh[7] +
                        k2.x * qh[8] + k2.y * qh[9] + k2.z * qh[10] + k2.w * qh[11] +
                        k3.x * qh[12] + k3.y * qh[13] + k3.z * qh[14] + k3.w * qh[15];
            ps[h][j] = (j <= s) ? acc * 0.25f : 0.f;
        }
    }
    __syncthreads();

    // softmax over j<=s: head = t>>5, 32 lanes
    {
        int h = t >> 5, lane = t & 31;
        float pm = -1e30f;
        for (int j = lane; j <= s; j += 32) pm = fmaxf(pm, ps[h][j]);
        #pragma unroll
        for (int m = 16; m > 0; m >>= 1) pm = fmaxf(pm, __shfl_xor(pm, m, 32));
        float psum = 0.f;
        for (int j = lane; j <= s; j += 32) {
            float e = __expf(ps[h][j] - pm);
            ps[h][j] = e;
            psum += e;
        }
        #pragma unroll
        for (int m = 16; m > 0; m >>= 1) psum += __shfl_xor(psum, m, 32);
        if (lane == 0) rl[h] = 1.0f / psum;
    }
    __syncthreads();

    // o from staged V (LDS): thread (col, half), 64 MACs
    {
        int h = col >> 4, jlo = half * 64;
        const float* vsh = B0;
        float a0 = 0, a1 = 0, a2 = 0, a3 = 0;
        #pragma unroll
        for (int j = 0; j < 64; j += 4) {
            a0 += ps[h][jlo + j] * vsh[(jlo + j) * 128 + col];
            a1 += ps[h][jlo + j + 1] * vsh[(jlo + j + 1) * 128 + col];
            a2 += ps[h][jlo + j + 2] * vsh[(jlo + j + 2) * 128 + col];
            a3 += ps[h][jlo + j + 3] * vsh[(jlo + j + 3) * 128 + col];
        }
        part[half][col] = (a0 + a1) + (a2 + a3);
    }
    __syncthreads();
    if (t < 128) orow[t] = (part[0][t] + part[1][t]) * rl[t >> 4];
    __syncthreads();

    // wo from staged LDS: thread (col, half), 64 MACs
    {
        int dlo = half * 64;
        const float* wosh = B0 + 16384;
        float a0 = 0, a1 = 0, a2 = 0, a3 = 0;
        #pragma unroll
        for (int d = 0; d < 64; d += 4) {
            a0 += orow[dlo + d] * wosh[(dlo + d) * 128 + col];
            a1 += orow[dlo + d + 1] * wosh[(dlo + d + 1) * 128 + col];
            a2 += orow[dlo + d + 2] * wosh[(dlo + d + 2) * 128 + col];
            a3 += orow[dlo + d + 3] * wosh[(dlo + d + 3) * 128 + col];
        }
        part[half][col] = (a0 + a1) + (a2 + a3);
    }
    __syncthreads();
    float xn = 0.f;
    if (t < 128) xn = xr + part[0][t] + part[1][t];
    float ss2 = block_sum256((t < 128) ? xn * xn : 0.f, scr);
    float r2 = 1.0f / sqrtf(ss2 * (1.0f / D) + EPS);
    if (t < 128) h2[t] = xn * r2 * n2w[t];
    // stage w1 chunk 0 (rows 0..31, 10912 floats) into buf0 before barrier
    float* buf[2] = {B0, B0 + 11008};
    {
        float4 tmp[11];
        pf_load<2728>(tmp, w1, t);
        pf_store<2728>(tmp, buf[0], t);
    }
    __syncthreads();

    // FFN1: 8 chunks (w1 x4, w3 x4), ping-pong with register prefetch.
    float a1a = 0, a1b = 0, a3a = 0, a3b = 0;
    #pragma unroll
    for (int p = 0; p < 8; ++p) {
        float4 tmp[11];
        if (p < 7) {
            const float* src = (p + 1 < 4) ? w1 + (p + 1) * 10912 : w3 + (p - 3) * 10912;
            pf_load<2728>(tmp, src, t);
        }
        const float* Bp = buf[p & 1];
        int d0 = (p & 3) * 32;
        float s0 = 0, s1 = 0;
        #pragma unroll
        for (int d = 0; d < 32; ++d) {
            float hv = h2[d0 + d];
            s0 += hv * Bp[d * HID + t];
            s1 += hv * Bp[d * HID + t + 256];  // OOB-safe within B0; masked later
        }
        if (p < 4) { a1a += s0; a1b += s1; }
        else { a3a += s0; a3b += s1; }
        if (p < 7) pf_store<2728>(tmp, buf[(p + 1) & 1], t);
        __syncthreads();
    }
    // silu+gate (register accs) + stage w2 chunk 0 (86 rows, 11008 floats)
    af[t] = (a1a / (1.0f + __expf(-a1a))) * a3a;
    if (t < 85) af[t + 256] = (a1b / (1.0f + __expf(-a1b))) * a3b;
    {
        float4 tmp[11];
        pf_load<2752>(tmp, w2, t);
        pf_store<2752>(tmp, buf[0], t);
    }
    __syncthreads();

    // FFN2: 4 chunks of rows {86,86,86,83}, ping-pong.
    float facc = 0.f;
    #pragma unroll
    for (int p = 0; p < 4; ++p) {
        float4 tmp[11];
        if (p < 3) pf_load<2752>(tmp, w2 + (p + 1) * 11008, t);
        const float* Bp = buf[p & 1];
        int rows = (p < 3) ? 86 : 83;
        int k0 = p * 86;
        int lo = half * 43;
        int hi = lo + 43; if (hi > rows) hi = rows;
        float a0 = 0, a1 = 0;
        #pragma unroll
        for (int u = 0; u < 43; u += 1) {
            int k = lo + u;
            if (k < hi) {
                float t0 = af[k0 + k] * Bp[k * 128 + col];
                if (u & 1) a1 += t0; else a0 += t0;
            }
        }
        facc += a0 + a1;
        if (p < 3) pf_store<2752>(tmp, buf[(p + 1) & 1], t);
        __syncthreads();
    }
    part[half][col] = facc;
    __syncthreads();
    float x2 = 0.f;
    if (t < 128) {
        x2 = xn + part[0][t] + part[1][t];
        if (MODE == 0) x[s * D + t] = x2;
    }
    float ss3 = block_sum256((t < 128) ? x2 * x2 : 0.f, scr);
    float r3 = 1.0f / sqrtf(ss3 * (1.0f / D) + EPS);

    if constexpr (MODE == 0) {
        if (t < 128) h2[t] = x2 * r3 * n1w[t];
        // stage wq -> B0[0..16384), wk -> B0[16384..32768)
        {
            const float4* q4 = (const float4*)wq;
            const float4* k4 = (const float4*)wk;
            float4* dA = (float4*)B0;
            float4* dB = (float4*)(B0 + 16384);
            #pragma unroll
            for (int i = 0; i < 16; ++i) {
                dA[t + i * 256] = q4[t + i * 256];
                dB[t + i * 256] = k4[t + i * 256];
            }
        }
        __syncthreads();
        // q (t<128 from A) / k (t>=128 from B): 128 MACs each
        {
            const float* W = (t < 128) ? B0 : (B0 + 16384);
            float a0 = 0, a1 = 0, a2 = 0, a3 = 0;
            #pragma unroll
            for (int d = 0; d < 128; d += 4) {
                a0 += h2[d] * W[d * 128 + col];
                a1 += h2[d + 1] * W[(d + 1) * 128 + col];
                a2 += h2[d + 2] * W[(d + 2) * 128 + col];
                a3 += h2[d + 3] * W[(d + 3) * 128 + col];
            }
            float qk = (a0 + a1) + (a2 + a3);
            if (t < 128) qrow[col] = qk;
            else krow[col] = qk;
        }
        __syncthreads();
        // stage wv -> A (q/k done reading)
        {
            const float4* v4 = (const float4*)wv;
            float4* dA = (float4*)B0;
            #pragma unroll
            for (int i = 0; i < 16; ++i) dA[t + i * 256] = v4[t + i * 256];
        }
        __syncthreads();
        // v: thread (col, half), 64 MACs
        {
            int dlo = half * 64;
            float a0 = 0, a1 = 0;
            #pragma unroll
            for (int d = 0; d < 64; d += 2) {
                a0 += h2[dlo + d] * B0[(dlo + d) * 128 + col];
                a1 += h2[dlo + d + 1] * B0[(dlo + d + 1) * 128 + col];
            }
            part[half][col] = a0 + a1;
        }
        __syncthreads();
        if (t < 128) {
            vo[s * D + t] = part[0][t] + part[1][t];
            int c = t & (HD - 1);
            int mm = c >> 1;
            float fr = (float)s * expf(-(float)mm * 1.15129254649702283e+00f);
            float cs = cosf(fr), sn = sinf(fr);
            int base = t & ~1;
            float qe = qrow[base], qod = qrow[base + 1];
            float ke = krow[base], kod = krow[base + 1];
            qo[s * D + t] = (c & 1) ? (qe * sn + qod * cs) : (qe * cs - qod * sn);
            ko[s * D + t] = (c & 1) ? (ke * sn + kod * cs) : (ke * cs - kod * sn);
        }
    } else {
        float y = (t < 128) ? x2 * r3 * fw[t] : 0.f;
        float nn = block_sum256(y * y, scr);
        if (t < 128) xng[t * SEQ + s] = y / sqrtf(nn);
    }
}

// K4: logits[s,v] = clip(mean_d(xn[s,d] <= vn[v,d] ? 1 : vn[v,d]))
__global__ __launch_bounds__(256) void k_logits(const float* __restrict__ xng,
                                                const float* __restrict__ w_raw,
                                                float* __restrict__ out) {
    __shared__ float xs[D * 64];
    __shared__ float vs[D * 32];
    __shared__ float nred[256];
    __shared__ float invn_s[32];
    int t = threadIdx.x;
    int sbase = (blockIdx.x & 1) * 64;
    int vbase = (blockIdx.x >> 1) * 32;
    for (int i = t; i < D * 64; i += 256) {
        int d = i >> 6, s2 = i & 63;
        xs[i] = xng[d * SEQ + sbase + s2];
    }
    for (int i = t; i < D * 32; i += 256) {
        int d = i >> 5, jj = i & 31;
        vs[i] = sigm(w_raw[d * V + vbase + jj]);
    }
    __syncthreads();
    {
        int colc = t & 31, dp = t >> 5;
        float p = 0.f;
        for (int u = 0; u < 16; ++u) {
            float vv = vs[(dp * 16 + u) * 32 + colc];
            p += vv * vv;
        }
        nred[t] = p;
    }
    __syncthreads();
    if (t < 32) {
        float sum = 0.f;
        for (int u = 0; u < 8; ++u) sum += nred[u * 32 + t];
        invn_s[t] = 1.0f / sqrtf(sum);
    }
    __syncthreads();
    for (int i = t; i < D * 32; i += 256) vs[i] *= invn_s[i & 31];
    __syncthreads();
    int vg = t & 15;
    int sg = t >> 4;
    float acc[4][2] = {};
    for (int d = 0; d < D; ++d) {
        float4 xq = *(const float4*)&xs[d * 64 + sg * 4];
        float2 vq = *(const float2*)&vs[d * 32 + vg * 2];
        acc[0][0] += (xq.x <= vq.x) ? 1.0f : vq.x;
        acc[0][1] += (xq.x <= vq.y) ? 1.0f : vq.y;
        acc[1][0] += (xq.y <= vq.x) ? 1.0f : vq.x;
        acc[1][1] += (xq.y <= vq.y) ? 1.0f : vq.y;
        acc[2][0] += (xq.z <= vq.x) ? 1.0f : vq.x;
        acc[2][1] += (xq.z <= vq.y) ? 1.0f : vq.y;
        acc[3][0] += (xq.w <= vq.x) ? 1.0f : vq.x;
        acc[3][1] += (xq.w <= vq.y) ? 1.0f : vq.y;
    }
    const float inv128 = 1.0f / 128.0f;
    #pragma unroll
    for (int si = 0; si < 4; ++si) {
        int s = sbase + sg * 4 + si;
        float2 ov;
        ov.x = fminf(fmaxf(acc[si][0] * inv128, 1e-6f), 1.0f - 1e-6f);
        ov.y = fminf(fmaxf(acc[si][1] * inv128, 1e-6f), 1.0f - 1e-6f);
        *(float2*)&out[s * V + vbase + vg * 2] = ov;
    }
}

extern "C" void kernel_launch(void* const* d_in, const int* in_sizes, int n_in,
                              void* d_out, int out_size, void* d_ws, size_t ws_size,
                              hipStream_t stream) {
    const int* idx = (const int*)d_in[0];
    const float* w_raw = (const float*)d_in[1];
    const float* n1w = (const float*)d_in[2];
    const float* n2w = (const float*)d_in[3];
    const float* wq = (const float*)d_in[4];
    const float* wk = (const float*)d_in[5];
    const float* wv = (const float*)d_in[6];
    const float* wo = (const float*)d_in[7];
    const float* w1 = (const float*)d_in[8];
    const float* w3 = (const float*)d_in[9];
    const float* w2 = (const float*)d_in[10];
    const float* fnw = (const float*)d_in[11];
    float* out = (float*)d_out;
    float* ws = (float*)d_ws;

    float* x    = ws;
    float* q1   = ws + 16384;
    float* k1   = ws + 32768;
    float* v1   = ws + 49152;
    float* q2   = ws + 65536;
    float* k2   = ws + 81920;
    float* v2   = ws + 98304;
    float* xng  = ws + 114688;
    float* sink = ws + 131072;

    k_embed_qkv<<<dim3(SEQ + 256), dim3(256), 0, stream>>>(
        idx, w_raw, wq, wk, wv, n1w, w1, w3, w2, wo, x, q1, k1, v1, sink);
    k_layer<0><<<dim3(SEQ), dim3(256), 0, stream>>>(
        q1, k1, v1, x, wo, n2w, w1, w3, w2,
        wq + D * D, wk + D * D, wv + D * D, n1w + D, q2, k2, v2,
        (const float*)nullptr, (float*)nullptr);
    k_layer<1><<<dim3(SEQ), dim3(256), 0, stream>>>(
        q2, k2, v2, x, wo + D * D, n2w + D, w1 + D * HID, w3 + D * HID,
        w2 + HID * D, (const float*)nullptr, (const float*)nullptr,
        (const float*)nullptr, (const float*)nullptr, (float*)nullptr,
        (float*)nullptr, (float*)nullptr, fnw, xng);
    k_logits<<<dim3(512), dim3(256), 0, stream>>>(xng, w_raw, out);
}

// Round 9
// 380.966 us; speedup vs baseline: 1.1372x; 1.1372x over previous
//
#include <hip/hip_runtime.h>
#include <math.h>

#define V 8192
#define D 128
#define NH 8
#define HD 16
#define SEQ 128
#define HID 341
#define EPS 1e-6f

__device__ __forceinline__ float sigm(float x) { return 1.0f / (1.0f + __expf(-x)); }
__device__ __forceinline__ float silu(float x) { return x / (1.0f + __expf(-x)); }

// 256-thread block-wide sum. scratch >= 4 floats. 2 barriers.
__device__ __forceinline__ float block_sum256(float v, float* scratch) {
    #pragma unroll
    for (int m = 32; m > 0; m >>= 1) v += __shfl_xor(v, m);
    if ((threadIdx.x & 63) == 0) scratch[threadIdx.x >> 6] = v;
    __syncthreads();
    float s = (scratch[0] + scratch[1]) + (scratch[2] + scratch[3]);
    __syncthreads();
    return s;
}

// K1: row blocks (s<SEQ): embed + rms + QKV(flat-stream) + rope.
//     warm blocks: vocab inv-norms (invn[v]) + L3 warm of layer weights.
__global__ __launch_bounds__(256, 1) void k_embed_qkv(
    const int* __restrict__ idx, const float* __restrict__ w_raw,
    const float* __restrict__ wq, const float* __restrict__ wk,
    const float* __restrict__ wv, const float* __restrict__ n1w,
    const float* __restrict__ w1, const float* __restrict__ w3,
    const float* __restrict__ w2, const float* __restrict__ wo,
    float* __restrict__ x, float* __restrict__ q, float* __restrict__ k,
    float* __restrict__ v, float* __restrict__ invn, float* __restrict__ sink) {
    int t = threadIdx.x;
    if (blockIdx.x >= SEQ) {
        // vocab norms: 32 v per block, 8 threads per v (16 d each)
        int vbase = (blockIdx.x - SEQ) * 32;
        int vloc = t >> 3, dp = t & 7;
        int vv = vbase + vloc;
        float acc = 0.f;
        #pragma unroll
        for (int u = 0; u < 16; ++u) {
            float val = sigm(w_raw[(dp * 16 + u) * V + vv]);
            acc += val * val;
        }
        #pragma unroll
        for (int m = 1; m < 8; m <<= 1) acc += __shfl_xor(acc, m);
        if (dp == 0) invn[vv] = 1.0f / sqrtf(acc);
        // L3-warm layer weights (cheap)
        int g = (blockIdx.x - SEQ) * 256 + t;
        float wa = 0.f;
        if (g < 21824) {
            float4 u1 = ((const float4*)w1)[g]; wa += u1.x + u1.y + u1.z + u1.w;
            float4 u3 = ((const float4*)w3)[g]; wa += u3.x + u3.y + u3.z + u3.w;
            float4 u2 = ((const float4*)w2)[g]; wa += u2.x + u2.y + u2.z + u2.w;
        }
        if (g < 8192) {
            float4 a = ((const float4*)wq)[g]; wa += a.x + a.y + a.z + a.w;
            float4 b = ((const float4*)wk)[g]; wa += b.x + b.y + b.z + b.w;
            float4 c = ((const float4*)wv)[g]; wa += c.x + c.y + c.z + c.w;
            float4 d = ((const float4*)wo)[g]; wa += d.x + d.y + d.z + d.w;
        }
        if (wa == 1234.5678f) sink[0] = wa;
        return;
    }
    __shared__ float h2[D], qacc[D], kacc[D], vacc[D], scr[4];
    int s = blockIdx.x;
    if (t < 128) { qacc[t] = 0.f; kacc[t] = 0.f; vacc[t] = 0.f; }
    float xv = 0.f;
    if (t < 128) {
        xv = sigm(w_raw[t * V + idx[s]]);
        x[s * D + t] = xv;
    }
    float ss = block_sum256(xv * xv, scr);
    float r = 1.0f / sqrtf(ss * (1.0f / D) + EPS);
    if (t < 128) h2[t] = xv * r * n1w[t];
    __syncthreads();
    // QKV: flat float4 streams + private acc4 + LDS atomics
    {
        const float4* q4 = (const float4*)wq;
        const float4* k4 = (const float4*)wk;
        const float4* v4 = (const float4*)wv;
        float qa0 = 0, qa1 = 0, qa2 = 0, qa3 = 0;
        float ka0 = 0, ka1 = 0, ka2 = 0, ka3 = 0;
        float va0 = 0, va1 = 0, va2 = 0, va3 = 0;
        #pragma unroll 4
        for (int j = 0; j < 16; ++j) {
            int i4 = t + 256 * j;
            int row = i4 >> 5;
            float hv = h2[row];
            float4 a = q4[i4], b = k4[i4], c = v4[i4];
            qa0 += hv * a.x; qa1 += hv * a.y; qa2 += hv * a.z; qa3 += hv * a.w;
            ka0 += hv * b.x; ka1 += hv * b.y; ka2 += hv * b.z; ka3 += hv * b.w;
            va0 += hv * c.x; va1 += hv * c.y; va2 += hv * c.z; va3 += hv * c.w;
        }
        int c0 = (t & 31) * 4;
        atomicAdd(&qacc[c0], qa0); atomicAdd(&qacc[c0 + 1], qa1);
        atomicAdd(&qacc[c0 + 2], qa2); atomicAdd(&qacc[c0 + 3], qa3);
        atomicAdd(&kacc[c0], ka0); atomicAdd(&kacc[c0 + 1], ka1);
        atomicAdd(&kacc[c0 + 2], ka2); atomicAdd(&kacc[c0 + 3], ka3);
        atomicAdd(&vacc[c0], va0); atomicAdd(&vacc[c0 + 1], va1);
        atomicAdd(&vacc[c0 + 2], va2); atomicAdd(&vacc[c0 + 3], va3);
    }
    __syncthreads();
    if (t < 128) {
        v[s * D + t] = vacc[t];
        int c = t & (HD - 1);
        int m = c >> 1;
        float fr = (float)s * expf(-(float)m * 1.15129254649702283e+00f);
        float cs = cosf(fr), sn = sinf(fr);
        int base = t & ~1;
        float qe = qacc[base], qod = qacc[base + 1];
        float ke = kacc[base], kod = kacc[base + 1];
        q[s * D + t] = (c & 1) ? (qe * sn + qod * cs) : (qe * cs - qod * sn);
        k[s * D + t] = (c & 1) ? (ke * sn + kod * cs) : (ke * cs - kod * sn);
    }
}

// K2/K3: fused layer per row; all weight GEMVs as flat coalesced float4
// streams with LDS-atomic reduction. grid=SEQ, block=256.
template <int MODE>
__global__ __launch_bounds__(256, 1) void k_layer(
    const float* __restrict__ q, const float* __restrict__ kg,
    const float* __restrict__ vg, float* __restrict__ x,
    const float* __restrict__ wo, const float* __restrict__ n2w,
    const float* __restrict__ w1, const float* __restrict__ w3,
    const float* __restrict__ w2, const float* __restrict__ wq,
    const float* __restrict__ wk, const float* __restrict__ wv,
    const float* __restrict__ n1w, float* __restrict__ qo, float* __restrict__ ko,
    float* __restrict__ vo, const float* __restrict__ fw, float* __restrict__ xng) {
    __shared__ float ps[NH][SEQ + 2];
    __shared__ float qs[D], orow[D], h2[D];
    __shared__ float oacc[D], pacc[D], qacc[D], kacc[D], vacc[D];
    __shared__ float afA[HID], afB[HID], af[HID];
    __shared__ float rl[NH];
    __shared__ float scr[4];
    int s = blockIdx.x, t = threadIdx.x;
    int col = t & 127, half = t >> 7;
    int cq = t & 31;
    int c0 = cq * 4;

    if (t < 128) {
        oacc[t] = 0.f; pacc[t] = 0.f;
        qacc[t] = 0.f; kacc[t] = 0.f; vacc[t] = 0.f;
    }
    for (int i = t; i < HID; i += 256) { afA[i] = 0.f; afB[i] = 0.f; }
    float xr = 0.f;
    if (t < 128) {
        qs[t] = q[s * D + t];
        xr = x[s * D + t];
    }
    __syncthreads();

    // scores: thread (j=col, heads half+2u); K rows as float4
    {
        int j = col;
        #pragma unroll
        for (int u = 0; u < 4; ++u) {
            int h = half + 2 * u;
            const float4* kp = (const float4*)&kg[j * D + h * HD];
            float4 k0 = kp[0], k1 = kp[1], k2 = kp[2], k3 = kp[3];
            const float* qh = &qs[h * HD];
            float acc = k0.x * qh[0] + k0.y * qh[1] + k0.z * qh[2] + k0.w * qh[3] +
                        k1.x * qh[4] + k1.y * qh[5] + k1.z * qh[6] + k1.w * qh[7] +
                        k2.x * qh[8] + k2.y * qh[9] + k2.z * qh[10] + k2.w * qh[11] +
                        k3.x * qh[12] + k3.y * qh[13] + k3.z * qh[14] + k3.w * qh[15];
            ps[h][j] = (j <= s) ? acc * 0.25f : 0.f;
        }
    }
    __syncthreads();

    // softmax over j<=s: head = t>>5, 32 lanes
    {
        int h = t >> 5, lane = t & 31;
        float pm = -1e30f;
        for (int j = lane; j <= s; j += 32) pm = fmaxf(pm, ps[h][j]);
        #pragma unroll
        for (int m = 16; m > 0; m >>= 1) pm = fmaxf(pm, __shfl_xor(pm, m, 32));
        float psum = 0.f;
        for (int j = lane; j <= s; j += 32) {
            float e = __expf(ps[h][j] - pm);
            ps[h][j] = e;
            psum += e;
        }
        #pragma unroll
        for (int m = 16; m > 0; m >>= 1) psum += __shfl_xor(psum, m, 32);
        if (lane == 0) rl[h] = 1.0f / psum;
    }
    __syncthreads();

    // o: V flat stream (ps zero beyond s); h fixed per thread = cq>>2
    {
        const float4* v4 = (const float4*)vg;
        int h = cq >> 2;
        float a0 = 0, a1 = 0, a2 = 0, a3 = 0;
        #pragma unroll 8
        for (int j = 0; j < 16; ++j) {
            int i4 = t + 256 * j;
            float p = ps[h][i4 >> 5];
            float4 vv = v4[i4];
            a0 += p * vv.x; a1 += p * vv.y; a2 += p * vv.z; a3 += p * vv.w;
        }
        atomicAdd(&oacc[c0], a0); atomicAdd(&oacc[c0 + 1], a1);
        atomicAdd(&oacc[c0 + 2], a2); atomicAdd(&oacc[c0 + 3], a3);
    }
    __syncthreads();
    if (t < 128) {
        orow[t] = oacc[t] * rl[t >> 4];
        oacc[t] = 0.f;  // reuse for FFN2
    }
    __syncthreads();

    // wo: flat stream
    {
        const float4* w4 = (const float4*)wo;
        float a0 = 0, a1 = 0, a2 = 0, a3 = 0;
        #pragma unroll 8
        for (int j = 0; j < 16; ++j) {
            int i4 = t + 256 * j;
            float ov = orow[i4 >> 5];
            float4 ww = w4[i4];
            a0 += ov * ww.x; a1 += ov * ww.y; a2 += ov * ww.z; a3 += ov * ww.w;
        }
        atomicAdd(&pacc[c0], a0); atomicAdd(&pacc[c0 + 1], a1);
        atomicAdd(&pacc[c0 + 2], a2); atomicAdd(&pacc[c0 + 3], a3);
    }
    __syncthreads();
    float xn = 0.f;
    if (t < 128) xn = xr + pacc[t];
    float ss2 = block_sum256((t < 128) ? xn * xn : 0.f, scr);
    float r2 = 1.0f / sqrtf(ss2 * (1.0f / D) + EPS);
    if (t < 128) h2[t] = xn * r2 * n2w[t];
    __syncthreads();

    // FFN1: w1/w3 flat streams; per-element LDS atomics (magic div by 341)
    {
        const float4* w14 = (const float4*)w1;
        const float4* w34 = (const float4*)w3;
        #pragma unroll 4
        for (int j = 0; j < 43; ++j) {
            int i4 = t + 256 * j;
            if (i4 < 10912) {
                float4 a = w14[i4];
                float4 b = w34[i4];
                int base = i4 * 4;
                int d0 = base / HID;
                int cc = base - d0 * HID;
                float hv0 = h2[d0];
                float hv1 = h2[(d0 + 1) & 127];
                {
                    atomicAdd(&afA[cc], hv0 * a.x);
                    atomicAdd(&afB[cc], hv0 * b.x);
                }
                {
                    int c = cc + 1; float hv = hv0;
                    if (c >= HID) { c -= HID; hv = hv1; }
                    atomicAdd(&afA[c], hv * a.y);
                    atomicAdd(&afB[c], hv * b.y);
                }
                {
                    int c = cc + 2; float hv = hv0;
                    if (c >= HID) { c -= HID; hv = hv1; }
                    atomicAdd(&afA[c], hv * a.z);
                    atomicAdd(&afB[c], hv * b.z);
                }
                {
                    int c = cc + 3; float hv = hv0;
                    if (c >= HID) { c -= HID; hv = hv1; }
                    atomicAdd(&afA[c], hv * a.w);
                    atomicAdd(&afB[c], hv * b.w);
                }
            }
        }
    }
    __syncthreads();
    for (int i = t; i < HID; i += 256) af[i] = silu(afA[i]) * afB[i];
    __syncthreads();

    // FFN2: w2 flat stream [k][128]; k = i4>>5, acc4 private, atomics to oacc
    {
        const float4* w24 = (const float4*)w2;
        float a0 = 0, a1 = 0, a2 = 0, a3 = 0;
        #pragma unroll 4
        for (int j = 0; j < 43; ++j) {
            int i4 = t + 256 * j;
            if (i4 < 10912) {
                float av = af[i4 >> 5];
                float4 ww = w24[i4];
                a0 += av * ww.x; a1 += av * ww.y; a2 += av * ww.z; a3 += av * ww.w;
            }
        }
        atomicAdd(&oacc[c0], a0); atomicAdd(&oacc[c0 + 1], a1);
        atomicAdd(&oacc[c0 + 2], a2); atomicAdd(&oacc[c0 + 3], a3);
    }
    __syncthreads();
    float x2 = 0.f;
    if (t < 128) {
        x2 = xn + oacc[t];
        if (MODE == 0) x[s * D + t] = x2;
    }
    float ss3 = block_sum256((t < 128) ? x2 * x2 : 0.f, scr);
    float r3 = 1.0f / sqrtf(ss3 * (1.0f / D) + EPS);

    if constexpr (MODE == 0) {
        if (t < 128) h2[t] = x2 * r3 * n1w[t];
        __syncthreads();
        // next-layer QKV: flat streams
        {
            const float4* q4 = (const float4*)wq;
            const float4* k4 = (const float4*)wk;
            const float4* v4 = (const float4*)wv;
            float qa0 = 0, qa1 = 0, qa2 = 0, qa3 = 0;
            float ka0 = 0, ka1 = 0, ka2 = 0, ka3 = 0;
            float va0 = 0, va1 = 0, va2 = 0, va3 = 0;
            #pragma unroll 4
            for (int j = 0; j < 16; ++j) {
                int i4 = t + 256 * j;
                float hv = h2[i4 >> 5];
                float4 a = q4[i4], b = k4[i4], c = v4[i4];
                qa0 += hv * a.x; qa1 += hv * a.y; qa2 += hv * a.z; qa3 += hv * a.w;
                ka0 += hv * b.x; ka1 += hv * b.y; ka2 += hv * b.z; ka3 += hv * b.w;
                va0 += hv * c.x; va1 += hv * c.y; va2 += hv * c.z; va3 += hv * c.w;
            }
            atomicAdd(&qacc[c0], qa0); atomicAdd(&qacc[c0 + 1], qa1);
            atomicAdd(&qacc[c0 + 2], qa2); atomicAdd(&qacc[c0 + 3], qa3);
            atomicAdd(&kacc[c0], ka0); atomicAdd(&kacc[c0 + 1], ka1);
            atomicAdd(&kacc[c0 + 2], ka2); atomicAdd(&kacc[c0 + 3], ka3);
            atomicAdd(&vacc[c0], va0); atomicAdd(&vacc[c0 + 1], va1);
            atomicAdd(&vacc[c0 + 2], va2); atomicAdd(&vacc[c0 + 3], va3);
        }
        __syncthreads();
        if (t < 128) {
            vo[s * D + t] = vacc[t];
            int c = t & (HD - 1);
            int mm = c >> 1;
            float fr = (float)s * expf(-(float)mm * 1.15129254649702283e+00f);
            float cs = cosf(fr), sn = sinf(fr);
            int base = t & ~1;
            float qe = qacc[base], qod = qacc[base + 1];
            float ke = kacc[base], kod = kacc[base + 1];
            qo[s * D + t] = (c & 1) ? (qe * sn + qod * cs) : (qe * cs - qod * sn);
            ko[s * D + t] = (c & 1) ? (ke * sn + kod * cs) : (ke * cs - kod * sn);
        }
    } else {
        float y = (t < 128) ? x2 * r3 * fw[t] : 0.f;
        float nn = block_sum256(y * y, scr);
        if (t < 128) xng[t * SEQ + s] = y / sqrtf(nn);
    }
}

// K4: logits[s,v] = clip(mean_d(xn[s,d] <= vn[v,d] ? 1 : vn[v,d]))
// invn precomputed by k_embed warm blocks.
__global__ __launch_bounds__(256) void k_logits(const float* __restrict__ xng,
                                                const float* __restrict__ w_raw,
                                                const float* __restrict__ invn,
                                                float* __restrict__ out) {
    __shared__ float xs[D * 64];
    __shared__ float vs[D * 32];
    int t = threadIdx.x;
    int sbase = (blockIdx.x & 1) * 64;
    int vbase = (blockIdx.x >> 1) * 32;
    for (int i = t; i < D * 64; i += 256) {
        int d = i >> 6, s2 = i & 63;
        xs[i] = xng[d * SEQ + sbase + s2];
    }
    for (int i = t; i < D * 32; i += 256) {
        int d = i >> 5, jj = i & 31;
        vs[i] = sigm(w_raw[d * V + vbase + jj]) * invn[vbase + jj];
    }
    __syncthreads();
    int vg = t & 15;
    int sg = t >> 4;
    float acc[4][2] = {};
    for (int d = 0; d < D; ++d) {
        float4 xq = *(const float4*)&xs[d * 64 + sg * 4];
        float2 vq = *(const float2*)&vs[d * 32 + vg * 2];
        acc[0][0] += (xq.x <= vq.x) ? 1.0f : vq.x;
        acc[0][1] += (xq.x <= vq.y) ? 1.0f : vq.y;
        acc[1][0] += (xq.y <= vq.x) ? 1.0f : vq.x;
        acc[1][1] += (xq.y <= vq.y) ? 1.0f : vq.y;
        acc[2][0] += (xq.z <= vq.x) ? 1.0f : vq.x;
        acc[2][1] += (xq.z <= vq.y) ? 1.0f : vq.y;
        acc[3][0] += (xq.w <= vq.x) ? 1.0f : vq.x;
        acc[3][1] += (xq.w <= vq.y) ? 1.0f : vq.y;
    }
    const float inv128 = 1.0f / 128.0f;
    #pragma unroll
    for (int si = 0; si < 4; ++si) {
        int s = sbase + sg * 4 + si;
        float2 ov;
        ov.x = fminf(fmaxf(acc[si][0] * inv128, 1e-6f), 1.0f - 1e-6f);
        ov.y = fminf(fmaxf(acc[si][1] * inv128, 1e-6f), 1.0f - 1e-6f);
        *(float2*)&out[s * V + vbase + vg * 2] = ov;
    }
}

extern "C" void kernel_launch(void* const* d_in, const int* in_sizes, int n_in,
                              void* d_out, int out_size, void* d_ws, size_t ws_size,
                              hipStream_t stream) {
    const int* idx = (const int*)d_in[0];
    const float* w_raw = (const float*)d_in[1];
    const float* n1w = (const float*)d_in[2];
    const float* n2w = (const float*)d_in[3];
    const float* wq = (const float*)d_in[4];
    const float* wk = (const float*)d_in[5];
    const float* wv = (const float*)d_in[6];
    const float* wo = (const float*)d_in[7];
    const float* w1 = (const float*)d_in[8];
    const float* w3 = (const float*)d_in[9];
    const float* w2 = (const float*)d_in[10];
    const float* fnw = (const float*)d_in[11];
    float* out = (float*)d_out;
    float* ws = (float*)d_ws;

    float* x    = ws;
    float* q1   = ws + 16384;
    float* k1   = ws + 32768;
    float* v1   = ws + 49152;
    float* q2   = ws + 65536;
    float* k2   = ws + 81920;
    float* v2   = ws + 98304;
    float* xng  = ws + 114688;
    float* sink = ws + 131072;
    float* invn = ws + 131088;

    k_embed_qkv<<<dim3(SEQ + 256), dim3(256), 0, stream>>>(
        idx, w_raw, wq, wk, wv, n1w, w1, w3, w2, wo, x, q1, k1, v1, invn, sink);
    k_layer<0><<<dim3(SEQ), dim3(256), 0, stream>>>(
        q1, k1, v1, x, wo, n2w, w1, w3, w2,
        wq + D * D, wk + D * D, wv + D * D, n1w + D, q2, k2, v2,
        (const float*)nullptr, (float*)nullptr);
    k_layer<1><<<dim3(SEQ), dim3(256), 0, stream>>>(
        q2, k2, v2, x, wo + D * D, n2w + D, w1 + D * HID, w3 + D * HID,
        w2 + HID * D, (const float*)nullptr, (const float*)nullptr,
        (const float*)nullptr, (const float*)nullptr, (float*)nullptr,
        (float*)nullptr, (float*)nullptr, fnw, xng);
    k_logits<<<dim3(512), dim3(256), 0, stream>>>(xng, w_raw, invn, out);
}